// Round 10
// baseline (333.243 us; speedup 1.0000x reference)
//
#include <hip/hip_runtime.h>
#include <hip/hip_fp16.h>

#define N_NODES 10000
#define E_EDGES 320000
#define NH 4
#define HOPS 3
#define WMAX 128

typedef _Float16 f16x8 __attribute__((ext_vector_type(8)));
typedef _Float16 f16x4 __attribute__((ext_vector_type(4)));
typedef float    f32x4 __attribute__((ext_vector_type(4)));

// ---------------- CSR build ----------------
__global__ void k_count(const int* __restrict__ dst, int* __restrict__ counts){
  int e = blockIdx.x*256 + threadIdx.x;
  if(e < E_EDGES) atomicAdd(&counts[dst[e]], 1);
}

__global__ __launch_bounds__(1024) void k_scan(const int* __restrict__ counts,
                                               int* __restrict__ row_ptr, int* __restrict__ fillp){
  __shared__ int sm[1024];
  int t = threadIdx.x;
  const int CH = 10;
  int base = t*CH;
  int loc[CH]; int sum = 0;
  #pragma unroll
  for(int i=0;i<CH;i++){
    int v = (base+i < N_NODES) ? counts[base+i] : 0;
    loc[i] = sum; sum += v;
  }
  sm[t] = sum; __syncthreads();
  for(int off=1; off<1024; off<<=1){
    int add = (t>=off) ? sm[t-off] : 0;
    __syncthreads();
    sm[t] += add;
    __syncthreads();
  }
  int excl = (t>0) ? sm[t-1] : 0;
  #pragma unroll
  for(int i=0;i<CH;i++){
    int n = base+i;
    if(n < N_NODES){
      int e = excl + loc[i];
      row_ptr[n] = e;
      fillp[n]   = e;
    }
  }
  if(t==1023) row_ptr[N_NODES] = sm[1023];
}

__global__ void k_fill(const int* __restrict__ src, const int* __restrict__ dst,
                       int* __restrict__ fillp, int* __restrict__ csr_eid, int* __restrict__ sorted_src){
  int e = blockIdx.x*256 + threadIdx.x;
  if(e < E_EDGES){
    int d = dst[e];
    int pos = atomicAdd(&fillp[d], 1);
    csr_eid[pos] = e;
    sorted_src[pos] = src[e];
  }
}

// ---------------- merged setup: xh0 | WsT transpose | b_edge ----------------
__global__ __launch_bounds__(256) void k_setup(const float* __restrict__ node_fts, _Float16* __restrict__ xh,
                       const float* __restrict__ Ws, _Float16* __restrict__ WsT,
                       const float* __restrict__ Wes, const float* __restrict__ a_edge,
                       float* __restrict__ b_edge){
  __shared__ float lds[32][65];
  int b = blockIdx.x, t = threadIdx.x;
  if(b < 1250){
    int i = b*256 + t;
    float4 v = *(const float4*)(node_fts + (size_t)i*4);
    f16x4 h = { (_Float16)v.x, (_Float16)v.y, (_Float16)v.z, (_Float16)v.w };
    *(f16x4*)(xh + (size_t)i*4) = h;
  } else if(b < 1346){
    int b2 = b - 1250;
    int hop = b2>>5, rem = b2&31, kt = rem>>3, ct = rem&7;
    int k0 = kt*32, c0 = ct*64;
    const float* wsrc = Ws + (size_t)hop*65536;
    #pragma unroll
    for(int i=0;i<8;i++){
      int u = t + i*256;
      int kk = u>>6, cc = u&63;
      lds[kk][cc] = wsrc[(size_t)(k0+kk)*512 + c0 + cc];
    }
    __syncthreads();
    _Float16* wdst = WsT + (size_t)hop*512*128;
    #pragma unroll
    for(int i=0;i<2;i++){
      int u = t + i*256;
      int c = u>>3, kq = (u&7)*4;
      f16x4 h = { (_Float16)lds[kq][c], (_Float16)lds[kq+1][c],
                  (_Float16)lds[kq+2][c], (_Float16)lds[kq+3][c] };
      *(f16x4*)(wdst + (size_t)(c0+c)*128 + k0 + kq) = h;
    }
  } else {
    int idx = (b-1346)*256 + t;
    if(idx < HOPS*64*NH){
      int hop = idx/(64*NH); int c = (idx/NH)%64; int h = idx%NH;
      const float* we = Wes + (size_t)hop*64*512 + (size_t)c*512 + h*128;
      const float* ae = a_edge + (size_t)hop*NH*128 + h*128;
      float s = 0.f;
      for(int f=0; f<128; f++) s += we[f] * ae[f];
      b_edge[idx] = s;
    }
  }
}

// ---------------- alpha via MFMA, CSR-ordered ----------------
__global__ __launch_bounds__(256) void k_alpha_mfma(const float* __restrict__ edge_fts,
                        const int* __restrict__ csr_eid, const float* __restrict__ b_edge,
                        float* __restrict__ ae_sorted){
  __shared__ float tile[64][20];
  int w = threadIdx.x>>6, l = threadIdx.x&63;
  int col = l&15, kgrp = l>>4;
  f16x8 bf0, bf1;
  #pragma unroll
  for(int j=0;j<8;j++){
    int k0 = 0*32 + kgrp*8 + j;
    int k1 = 1*32 + kgrp*8 + j;
    float v0 = 0.f, v1 = 0.f;
    if(col < 12){
      int hop = col>>2, h = col&3;
      v0 = b_edge[hop*256 + k0*4 + h];
      v1 = b_edge[hop*256 + k1*4 + h];
    }
    bf0[j] = (_Float16)v0;
    bf1[j] = (_Float16)v1;
  }
  int pos0 = blockIdx.x*64 + w*16;
  int erow = csr_eid[pos0 + (l&15)];
  const float* ef = edge_fts + (size_t)erow*64 + kgrp*8;
  f32x4 acc = {0.f,0.f,0.f,0.f};
  {
    float4 x0 = *(const float4*)(ef);
    float4 x1 = *(const float4*)(ef + 4);
    f16x8 a = { (_Float16)x0.x,(_Float16)x0.y,(_Float16)x0.z,(_Float16)x0.w,
                (_Float16)x1.x,(_Float16)x1.y,(_Float16)x1.z,(_Float16)x1.w };
    acc = __builtin_amdgcn_mfma_f32_16x16x32_f16(a, bf0, acc, 0, 0, 0);
  }
  {
    float4 x0 = *(const float4*)(ef + 32);
    float4 x1 = *(const float4*)(ef + 36);
    f16x8 a = { (_Float16)x0.x,(_Float16)x0.y,(_Float16)x0.z,(_Float16)x0.w,
                (_Float16)x1.x,(_Float16)x1.y,(_Float16)x1.z,(_Float16)x1.w };
    acc = __builtin_amdgcn_mfma_f32_16x16x32_f16(a, bf1, acc, 0, 0, 0);
  }
  int crow = (l>>4)*4;
  #pragma unroll
  for(int r=0;r<4;r++) tile[w*16 + crow + r][col] = acc[r];
  __syncthreads();
  int u = threadIdx.x;
  int edge = u>>2, q = u&3;
  if(q < 3){
    *(float4*)(ae_sorted + (size_t)q*E_EDGES*4 + ((size_t)(blockIdx.x*64 + edge))*4)
      = *(const float4*)&tile[edge][q*4];
  }
}

// ---------------- MFMA proj (64 rows x 1 head=128 cols) + fused s_src/s_dst ----------------
__global__ __launch_bounds__(256) void k_projm(const _Float16* __restrict__ xh,
                       const _Float16* __restrict__ Wt, __half* __restrict__ h_all,
                       const float* __restrict__ asrc, const float* __restrict__ adst,
                       float* __restrict__ s_src, float* __restrict__ s_dst){
  __shared__ __align__(16) __half tile[64][136];
  int w = threadIdx.x>>6, l = threadIdx.x&63;
  int rowb = blockIdx.x*64;
  int row0 = rowb + w*16;
  int head = blockIdx.y;
  int col0 = head*128;
  int ar = l&15, ac = (l>>4)*8;
  f32x4 acc[8];
  #pragma unroll
  for(int q=0;q<8;q++) acc[q] = (f32x4){0.f,0.f,0.f,0.f};
  #pragma unroll
  for(int kk=0; kk<4; kk++){
    f16x8 a = *(const f16x8*)(xh + (size_t)(row0+ar)*128 + kk*32 + ac);
    #pragma unroll
    for(int q=0;q<8;q++){
      f16x8 b = *(const f16x8*)(Wt + (size_t)(col0 + q*16 + ar)*128 + kk*32 + ac);
      acc[q] = __builtin_amdgcn_mfma_f32_16x16x32_f16(a, b, acc[q], 0, 0, 0);
    }
  }
  int crow = (l>>4)*4, ccol = l&15;
  // fused s partials: s[row,head] = sum_c h[row,col0+c]*a[col0+c]
  {
    float ps[4] = {0.f,0.f,0.f,0.f}, pd[4] = {0.f,0.f,0.f,0.f};
    #pragma unroll
    for(int q=0;q<8;q++){
      float as_ = asrc[col0 + q*16 + ccol];
      float ad_ = adst[col0 + q*16 + ccol];
      #pragma unroll
      for(int r=0;r<4;r++){ ps[r] += acc[q][r]*as_; pd[r] += acc[q][r]*ad_; }
    }
    #pragma unroll
    for(int m=1;m<16;m<<=1){
      #pragma unroll
      for(int r=0;r<4;r++){ ps[r] += __shfl_xor(ps[r], m); pd[r] += __shfl_xor(pd[r], m); }
    }
    if(ccol == 0){
      #pragma unroll
      for(int r=0;r<4;r++){
        int row = row0 + crow + r;
        if(row < N_NODES){
          s_src[(size_t)row*4 + head] = ps[r];
          s_dst[(size_t)row*4 + head] = pd[r];
        }
      }
    }
  }
  #pragma unroll
  for(int q=0;q<8;q++){
    #pragma unroll
    for(int r=0;r<4;r++)
      tile[w*16 + crow + r][q*16 + ccol] = __float2half(acc[q][r]);
  }
  __syncthreads();
  #pragma unroll
  for(int i=0;i<4;i++){
    int u = threadIdx.x + i*256;     // 1024 units of 8 halves; 64 rows x 16
    int row = u>>4, cq = (u&15)*8;
    int grow = rowb + row;
    if(grow < N_NODES)
      *(float4*)(h_all + (size_t)grow*512 + col0 + cq) = *(const float4*)&tile[row][cq];
  }
}

// ---------------- fused softmax + aggregate: wave/node, 8 loads in flight ----------------
__global__ __launch_bounds__(256) void k_softagg(
    const float* __restrict__ ae, const float* __restrict__ s_src,
    const float* __restrict__ s_dst, const int* __restrict__ sorted_src,
    const int* __restrict__ row_ptr, const __half* __restrict__ h_all,
    float* __restrict__ ew_fb, float* __restrict__ xout, _Float16* __restrict__ xh)
{
  __shared__ float ws4[4][WMAX*4];
  __shared__ int   ssm4[4][WMAX];
  int wv = threadIdx.x>>6, l = threadIdx.x&63;
  int n = blockIdx.x*4 + wv;
  if(n >= N_NODES) return;
  int start = row_ptr[n], end = row_ptr[n+1];
  int deg = end - start;
  bool fits = (deg <= WMAX);
  float* ws = ws4[wv];
  int*   ssm = ssm4[wv];

  float4 sd = *(const float4*)(s_dst + (size_t)n*4);
  float m0=-1e30f, m1=-1e30f, m2=-1e30f, m3=-1e30f;
  float aR[2][4];

  // ---- logits + max ----
  if(fits){
    #pragma unroll
    for(int k=0;k<2;k++){
      int idx = l + k*64;
      if(idx < deg){
        int pos = start + idx;
        int s = sorted_src[pos];
        float4 ss = *(const float4*)(s_src + (size_t)s*4);
        float4 av = *(const float4*)(ae + (size_t)pos*4);
        float a0 = ss.x+sd.x+av.x; a0=(a0>0.f)?a0:0.2f*a0;
        float a1 = ss.y+sd.y+av.y; a1=(a1>0.f)?a1:0.2f*a1;
        float a2 = ss.z+sd.z+av.z; a2=(a2>0.f)?a2:0.2f*a2;
        float a3 = ss.w+sd.w+av.w; a3=(a3>0.f)?a3:0.2f*a3;
        aR[k][0]=a0; aR[k][1]=a1; aR[k][2]=a2; aR[k][3]=a3;
        ssm[idx] = s;
        m0=fmaxf(m0,a0); m1=fmaxf(m1,a1); m2=fmaxf(m2,a2); m3=fmaxf(m3,a3);
      }
    }
  } else {
    for(int pos=start+l; pos<end; pos+=64){
      int s = sorted_src[pos];
      float4 ss = *(const float4*)(s_src + (size_t)s*4);
      float4 av = *(const float4*)(ae + (size_t)pos*4);
      float a0 = ss.x+sd.x+av.x; a0=(a0>0.f)?a0:0.2f*a0;
      float a1 = ss.y+sd.y+av.y; a1=(a1>0.f)?a1:0.2f*a1;
      float a2 = ss.z+sd.z+av.z; a2=(a2>0.f)?a2:0.2f*a2;
      float a3 = ss.w+sd.w+av.w; a3=(a3>0.f)?a3:0.2f*a3;
      *(float4*)(ew_fb + (size_t)pos*4) = make_float4(a0,a1,a2,a3);
      m0=fmaxf(m0,a0); m1=fmaxf(m1,a1); m2=fmaxf(m2,a2); m3=fmaxf(m3,a3);
    }
  }
  #pragma unroll
  for(int off=32; off; off>>=1){
    m0=fmaxf(m0,__shfl_xor(m0,off)); m1=fmaxf(m1,__shfl_xor(m1,off));
    m2=fmaxf(m2,__shfl_xor(m2,off)); m3=fmaxf(m3,__shfl_xor(m3,off));
  }

  // ---- exp + sum ----
  float s0=0.f,s1=0.f,s2=0.f,s3=0.f;
  if(fits){
    #pragma unroll
    for(int k=0;k<2;k++){
      int idx = l + k*64;
      if(idx < deg){
        float w0=__expf(aR[k][0]-m0), w1=__expf(aR[k][1]-m1);
        float w2=__expf(aR[k][2]-m2), w3=__expf(aR[k][3]-m3);
        int sl = idx*4;
        ws[sl]=w0; ws[sl+1]=w1; ws[sl+2]=w2; ws[sl+3]=w3;
        s0+=w0; s1+=w1; s2+=w2; s3+=w3;
      }
    }
  } else {
    for(int pos=start+l; pos<end; pos+=64){
      float4 a = *(const float4*)(ew_fb + (size_t)pos*4);
      float w0=__expf(a.x-m0), w1=__expf(a.y-m1), w2=__expf(a.z-m2), w3=__expf(a.w-m3);
      *(float4*)(ew_fb + (size_t)pos*4) = make_float4(w0,w1,w2,w3);
      s0+=w0; s1+=w1; s2+=w2; s3+=w3;
    }
  }
  #pragma unroll
  for(int off=32; off; off>>=1){
    s0+=__shfl_xor(s0,off); s1+=__shfl_xor(s1,off);
    s2+=__shfl_xor(s2,off); s3+=__shfl_xor(s3,off);
  }

  // ---- gather-aggregate: 8 loads in flight, 4 static acc sets ----
  int h = l>>4, f8 = (l&15)*8;
  float dh = (h==0)?s0:((h==1)?s1:((h==2)?s2:s3));
  float inv = 1.f/(dh + 1e-16f);
  float ac[4][8] = {{0,0,0,0,0,0,0,0},{0,0,0,0,0,0,0,0},{0,0,0,0,0,0,0,0},{0,0,0,0,0,0,0,0}};
  int hoff = (h<<7) + f8;
  int sl = 0;
  if(fits){
    for(; sl+8 <= deg; sl+=8){
      float wg[8]; float4 rr[8];
      #pragma unroll
      for(int j=0;j<8;j++){
        int s = ssm[sl+j];
        wg[j] = ws[(sl+j)*4+h];
        rr[j] = *(const float4*)(h_all + (size_t)s*512 + hoff);
      }
      #pragma unroll
      for(int j=0;j<8;j++){
        const __half2* hh = (const __half2*)&rr[j];
        #pragma unroll
        for(int q=0;q<4;q++){
          float2 v = __half22float2(hh[q]);
          ac[j&3][2*q]   += wg[j]*v.x;
          ac[j&3][2*q+1] += wg[j]*v.y;
        }
      }
    }
    for(; sl+4 <= deg; sl+=4){
      float wg[4]; float4 rr[4];
      #pragma unroll
      for(int j=0;j<4;j++){
        int s = ssm[sl+j];
        wg[j] = ws[(sl+j)*4+h];
        rr[j] = *(const float4*)(h_all + (size_t)s*512 + hoff);
      }
      #pragma unroll
      for(int j=0;j<4;j++){
        const __half2* hh = (const __half2*)&rr[j];
        #pragma unroll
        for(int q=0;q<4;q++){
          float2 v = __half22float2(hh[q]);
          ac[j][2*q]   += wg[j]*v.x;
          ac[j][2*q+1] += wg[j]*v.y;
        }
      }
    }
    for(; sl < deg; sl++){
      int s = ssm[sl]; float w = ws[sl*4+h];
      float4 r = *(const float4*)(h_all + (size_t)s*512 + hoff);
      const __half2* hh = (const __half2*)&r;
      #pragma unroll
      for(int q=0;q<4;q++){
        float2 v = __half22float2(hh[q]);
        ac[0][2*q]   += w*v.x;
        ac[0][2*q+1] += w*v.y;
      }
    }
  } else {
    for(; sl < deg; sl++){
      int s = sorted_src[start+sl]; float w = ew_fb[(size_t)(start+sl)*4+h];
      float4 r = *(const float4*)(h_all + (size_t)s*512 + hoff);
      const __half2* hh = (const __half2*)&r;
      #pragma unroll
      for(int q=0;q<4;q++){
        float2 v = __half22float2(hh[q]);
        ac[0][2*q]   += w*v.x;
        ac[0][2*q+1] += w*v.y;
      }
    }
  }
  float acc[8];
  #pragma unroll
  for(int i=0;i<8;i++){
    acc[i] = (ac[0][i]+ac[1][i]) + (ac[2][i]+ac[3][i]);
    acc[i] *= inv;
    acc[i] += __shfl_xor(acc[i], 16);
    acc[i] += __shfl_xor(acc[i], 32);
    acc[i] *= 0.25f;
  }
  if(l < 16){
    int f0 = l*8;
    *(float4*)(xout + (size_t)n*128 + f0)     = make_float4(acc[0],acc[1],acc[2],acc[3]);
    *(float4*)(xout + (size_t)n*128 + f0 + 4) = make_float4(acc[4],acc[5],acc[6],acc[7]);
    if(xh){
      f16x8 hv = { (_Float16)acc[0],(_Float16)acc[1],(_Float16)acc[2],(_Float16)acc[3],
                   (_Float16)acc[4],(_Float16)acc[5],(_Float16)acc[6],(_Float16)acc[7] };
      *(f16x8*)(xh + (size_t)n*128 + f0) = hv;
    }
  }
}

// ---------------- gated residual, GEMM-tiled ----------------
__global__ __launch_bounds__(256) void k_gate2(const float* __restrict__ prior, const float* __restrict__ curr,
                       const float* __restrict__ Wp, const float* __restrict__ Wc,
                       float* __restrict__ xnew, _Float16* __restrict__ xh){
  __shared__ float pr[32][132];
  __shared__ float cu[32][132];
  int t = threadIdx.x;
  int n0 = blockIdx.x*32;
  int c0 = blockIdx.y*64;
  #pragma unroll
  for(int i=0;i<4;i++){
    int u = t + i*256;
    int row = u>>5, c4 = (u&31)<<2;
    float4 v = make_float4(0.f,0.f,0.f,0.f), w = v;
    if(n0+row < N_NODES){
      v = *(const float4*)(prior + (size_t)(n0+row)*128 + c4);
      w = *(const float4*)(curr  + (size_t)(n0+row)*128 + c4);
    }
    *(float4*)&pr[row][c4] = v;
    *(float4*)&cu[row][c4] = w;
  }
  __syncthreads();
  int tc = t&15, tr = t>>4;
  int r0 = tr*2, cc = c0 + tc*4;
  float accp[2][4] = {{0.f,0.f,0.f,0.f},{0.f,0.f,0.f,0.f}};
  float accc[2][4] = {{0.f,0.f,0.f,0.f},{0.f,0.f,0.f,0.f}};
  #pragma unroll 4
  for(int k=0;k<128;k++){
    float4 wp = *(const float4*)(Wp + (size_t)k*128 + cc);
    float4 wc = *(const float4*)(Wc + (size_t)k*128 + cc);
    #pragma unroll
    for(int i=0;i<2;i++){
      float ap = pr[r0+i][k], ac = cu[r0+i][k];
      accp[i][0]+=ap*wp.x; accp[i][1]+=ap*wp.y; accp[i][2]+=ap*wp.z; accp[i][3]+=ap*wp.w;
      accc[i][0]+=ac*wc.x; accc[i][1]+=ac*wc.y; accc[i][2]+=ac*wc.z; accc[i][3]+=ac*wc.w;
    }
  }
  #pragma unroll
  for(int i=0;i<2;i++){
    int row = n0 + r0 + i;
    if(row < N_NODES){
      float oj[4];
      #pragma unroll
      for(int j=0;j<4;j++){
        float z = accp[i][j]+accc[i][j];
        float g = 1.f/(1.f+__expf(-z));
        oj[j] = g*cu[r0+i][cc + j] + (1.f-g)*pr[r0+i][cc + j];
      }
      *(float4*)(xnew + (size_t)row*128 + cc) = make_float4(oj[0],oj[1],oj[2],oj[3]);
      if(xh){
        f16x4 hv = { (_Float16)oj[0], (_Float16)oj[1], (_Float16)oj[2], (_Float16)oj[3] };
        *(f16x4*)(xh + (size_t)row*128 + cc) = hv;
      }
    }
  }
}

extern "C" void kernel_launch(void* const* d_in, const int* in_sizes, int n_in,
                              void* d_out, int out_size, void* d_ws, size_t ws_size,
                              hipStream_t stream){
  (void)in_sizes; (void)n_in; (void)out_size; (void)ws_size;
  const float* node_fts = (const float*)d_in[0];
  const float* edge_fts = (const float*)d_in[1];
  const int*   edges    = (const int*)d_in[2];
  const float* Ws       = (const float*)d_in[3];
  const float* Wes      = (const float*)d_in[4];
  const float* a_src    = (const float*)d_in[5];
  const float* a_dst    = (const float*)d_in[6];
  const float* a_edge   = (const float*)d_in[7];
  const float* W_prior  = (const float*)d_in[8];
  const float* W_curr   = (const float*)d_in[9];

  char* ws = (char*)d_ws;
  size_t off = 0;
  auto alloc = [&](size_t bytes)->void*{
    void* p = ws + off;
    off += (bytes + 255) & ~(size_t)255;
    return p;
  };
  int*       counts     = (int*)      alloc((size_t)N_NODES*4);
  int*       row_ptr    = (int*)      alloc((size_t)(N_NODES+1)*4);
  int*       fillp      = (int*)      alloc((size_t)N_NODES*4);
  int*       csr_eid    = (int*)      alloc((size_t)E_EDGES*4);
  int*       sorted_src = (int*)      alloc((size_t)E_EDGES*4);
  float*     b_edge     = (float*)    alloc((size_t)HOPS*64*NH*4);
  float*     ae_sorted  = (float*)    alloc((size_t)HOPS*E_EDGES*NH*4);
  __half*    h_all      = (__half*)   alloc((size_t)N_NODES*512*2);
  float*     s_src      = (float*)    alloc((size_t)N_NODES*NH*4);
  float*     s_dst      = (float*)    alloc((size_t)N_NODES*NH*4);
  float*     ew_fb      = (float*)    alloc((size_t)E_EDGES*NH*4);
  float*     xbuf       = (float*)    alloc((size_t)N_NODES*128*4);
  float*     curbuf     = (float*)    alloc((size_t)N_NODES*128*4);
  _Float16*  xh         = (_Float16*) alloc((size_t)10112*128*2);   // padded rows for MFMA over-read
  _Float16*  WsT        = (_Float16*) alloc((size_t)HOPS*512*128*2);

  const int* src = edges;
  const int* dst = edges + E_EDGES;

  (void)hipMemsetAsync(counts, 0, (size_t)N_NODES*4, stream);
  k_count<<<(E_EDGES+255)/256, 256, 0, stream>>>(dst, counts);
  k_scan<<<1, 1024, 0, stream>>>(counts, row_ptr, fillp);
  k_fill<<<(E_EDGES+255)/256, 256, 0, stream>>>(src, dst, fillp, csr_eid, sorted_src);
  k_setup<<<1349, 256, 0, stream>>>(node_fts, xh, Ws, WsT, Wes, a_edge, b_edge);
  k_alpha_mfma<<<5000, 256, 0, stream>>>(edge_fts, csr_eid, b_edge, ae_sorted);

  for(int hop=0; hop<HOPS; hop++){
    k_projm<<<dim3(157, 4), 256, 0, stream>>>(xh, WsT + (size_t)hop*512*128, h_all,
                                              a_src + (size_t)hop*512, a_dst + (size_t)hop*512,
                                              s_src, s_dst);
    float* xout = (hop==0) ? xbuf : curbuf;
    k_softagg<<<2500, 256, 0, stream>>>(ae_sorted + (size_t)hop*E_EDGES*4, s_src, s_dst,
                                        sorted_src, row_ptr, h_all, ew_fb, xout,
                                        (hop==0) ? xh : (_Float16*)nullptr);
    if(hop > 0){
      float* xnew = (hop == HOPS-1) ? (float*)d_out : xbuf;
      k_gate2<<<dim3(313, 2), 256, 0, stream>>>(xbuf, curbuf, W_prior, W_curr, xnew,
                                                (hop < HOPS-1) ? xh : (_Float16*)nullptr);
    }
  }
}

// Round 11
// 314.160 us; speedup vs baseline: 1.0607x; 1.0607x over previous
//
#include <hip/hip_runtime.h>
#include <hip/hip_fp16.h>

#define N_NODES 10000
#define E_EDGES 320000
#define NH 4
#define HOPS 3
#define WMAX 128

typedef _Float16 f16x8 __attribute__((ext_vector_type(8)));
typedef _Float16 f16x4 __attribute__((ext_vector_type(4)));
typedef float    f32x4 __attribute__((ext_vector_type(4)));

// ---------------- CSR build ----------------
__global__ void k_count(const int* __restrict__ dst, int* __restrict__ counts){
  int e = blockIdx.x*256 + threadIdx.x;
  if(e < E_EDGES) atomicAdd(&counts[dst[e]], 1);
}

__global__ __launch_bounds__(1024) void k_scan(const int* __restrict__ counts,
                                               int* __restrict__ row_ptr, int* __restrict__ fillp){
  __shared__ int sm[1024];
  int t = threadIdx.x;
  const int CH = 10;
  int base = t*CH;
  int loc[CH]; int sum = 0;
  #pragma unroll
  for(int i=0;i<CH;i++){
    int v = (base+i < N_NODES) ? counts[base+i] : 0;
    loc[i] = sum; sum += v;
  }
  sm[t] = sum; __syncthreads();
  for(int off=1; off<1024; off<<=1){
    int add = (t>=off) ? sm[t-off] : 0;
    __syncthreads();
    sm[t] += add;
    __syncthreads();
  }
  int excl = (t>0) ? sm[t-1] : 0;
  #pragma unroll
  for(int i=0;i<CH;i++){
    int n = base+i;
    if(n < N_NODES){
      int e = excl + loc[i];
      row_ptr[n] = e;
      fillp[n]   = e;
    }
  }
  if(t==1023) row_ptr[N_NODES] = sm[1023];
}

__global__ void k_fill(const int* __restrict__ src, const int* __restrict__ dst,
                       int* __restrict__ fillp, int* __restrict__ csr_eid, int* __restrict__ sorted_src){
  int e = blockIdx.x*256 + threadIdx.x;
  if(e < E_EDGES){
    int d = dst[e];
    int pos = atomicAdd(&fillp[d], 1);
    csr_eid[pos] = e;
    sorted_src[pos] = src[e];
  }
}

// ---------------- merged setup: xh0 | WsT transpose | b_edge ----------------
__global__ __launch_bounds__(256) void k_setup(const float* __restrict__ node_fts, _Float16* __restrict__ xh,
                       const float* __restrict__ Ws, _Float16* __restrict__ WsT,
                       const float* __restrict__ Wes, const float* __restrict__ a_edge,
                       float* __restrict__ b_edge){
  __shared__ float lds[32][65];
  int b = blockIdx.x, t = threadIdx.x;
  if(b < 1250){
    int i = b*256 + t;
    float4 v = *(const float4*)(node_fts + (size_t)i*4);
    f16x4 h = { (_Float16)v.x, (_Float16)v.y, (_Float16)v.z, (_Float16)v.w };
    *(f16x4*)(xh + (size_t)i*4) = h;
  } else if(b < 1346){
    int b2 = b - 1250;
    int hop = b2>>5, rem = b2&31, kt = rem>>3, ct = rem&7;
    int k0 = kt*32, c0 = ct*64;
    const float* wsrc = Ws + (size_t)hop*65536;
    #pragma unroll
    for(int i=0;i<8;i++){
      int u = t + i*256;
      int kk = u>>6, cc = u&63;
      lds[kk][cc] = wsrc[(size_t)(k0+kk)*512 + c0 + cc];
    }
    __syncthreads();
    _Float16* wdst = WsT + (size_t)hop*512*128;
    #pragma unroll
    for(int i=0;i<2;i++){
      int u = t + i*256;
      int c = u>>3, kq = (u&7)*4;
      f16x4 h = { (_Float16)lds[kq][c], (_Float16)lds[kq+1][c],
                  (_Float16)lds[kq+2][c], (_Float16)lds[kq+3][c] };
      *(f16x4*)(wdst + (size_t)(c0+c)*128 + k0 + kq) = h;
    }
  } else {
    int idx = (b-1346)*256 + t;
    if(idx < HOPS*64*NH){
      int hop = idx/(64*NH); int c = (idx/NH)%64; int h = idx%NH;
      const float* we = Wes + (size_t)hop*64*512 + (size_t)c*512 + h*128;
      const float* ae = a_edge + (size_t)hop*NH*128 + h*128;
      float s = 0.f;
      for(int f=0; f<128; f++) s += we[f] * ae[f];
      b_edge[idx] = s;
    }
  }
}

// ---------------- alpha via MFMA, CSR-ordered ----------------
__global__ __launch_bounds__(256) void k_alpha_mfma(const float* __restrict__ edge_fts,
                        const int* __restrict__ csr_eid, const float* __restrict__ b_edge,
                        float* __restrict__ ae_sorted){
  __shared__ float tile[64][20];
  int w = threadIdx.x>>6, l = threadIdx.x&63;
  int col = l&15, kgrp = l>>4;
  f16x8 bf0, bf1;
  #pragma unroll
  for(int j=0;j<8;j++){
    int k0 = 0*32 + kgrp*8 + j;
    int k1 = 1*32 + kgrp*8 + j;
    float v0 = 0.f, v1 = 0.f;
    if(col < 12){
      int hop = col>>2, h = col&3;
      v0 = b_edge[hop*256 + k0*4 + h];
      v1 = b_edge[hop*256 + k1*4 + h];
    }
    bf0[j] = (_Float16)v0;
    bf1[j] = (_Float16)v1;
  }
  int pos0 = blockIdx.x*64 + w*16;
  int erow = csr_eid[pos0 + (l&15)];
  const float* ef = edge_fts + (size_t)erow*64 + kgrp*8;
  f32x4 acc = {0.f,0.f,0.f,0.f};
  {
    float4 x0 = *(const float4*)(ef);
    float4 x1 = *(const float4*)(ef + 4);
    f16x8 a = { (_Float16)x0.x,(_Float16)x0.y,(_Float16)x0.z,(_Float16)x0.w,
                (_Float16)x1.x,(_Float16)x1.y,(_Float16)x1.z,(_Float16)x1.w };
    acc = __builtin_amdgcn_mfma_f32_16x16x32_f16(a, bf0, acc, 0, 0, 0);
  }
  {
    float4 x0 = *(const float4*)(ef + 32);
    float4 x1 = *(const float4*)(ef + 36);
    f16x8 a = { (_Float16)x0.x,(_Float16)x0.y,(_Float16)x0.z,(_Float16)x0.w,
                (_Float16)x1.x,(_Float16)x1.y,(_Float16)x1.z,(_Float16)x1.w };
    acc = __builtin_amdgcn_mfma_f32_16x16x32_f16(a, bf1, acc, 0, 0, 0);
  }
  int crow = (l>>4)*4;
  #pragma unroll
  for(int r=0;r<4;r++) tile[w*16 + crow + r][col] = acc[r];
  __syncthreads();
  int u = threadIdx.x;
  int edge = u>>2, q = u&3;
  if(q < 3){
    *(float4*)(ae_sorted + (size_t)q*E_EDGES*4 + ((size_t)(blockIdx.x*64 + edge))*4)
      = *(const float4*)&tile[edge][q*4];
  }
}

// ---------------- MFMA proj + LDS repack for coalesced stores ----------------
__global__ __launch_bounds__(256) void k_projm(const _Float16* __restrict__ xh,
                       const _Float16* __restrict__ Wt, __half* __restrict__ h_all){
  __shared__ __align__(16) __half tile[64][72];
  int w = threadIdx.x>>6, l = threadIdx.x&63;
  int rowb = blockIdx.x*64;
  int row0 = rowb + w*16;
  int col0 = blockIdx.y*64;
  int ar = l&15, ac = (l>>4)*8;
  f32x4 acc0 = {0.f,0.f,0.f,0.f}, acc1 = acc0, acc2 = acc0, acc3 = acc0;
  #pragma unroll
  for(int kk=0; kk<4; kk++){
    f16x8 a  = *(const f16x8*)(xh + (size_t)(row0+ar)*128 + kk*32 + ac);
    f16x8 b0 = *(const f16x8*)(Wt + (size_t)(col0 +  0 + ar)*128 + kk*32 + ac);
    f16x8 b1 = *(const f16x8*)(Wt + (size_t)(col0 + 16 + ar)*128 + kk*32 + ac);
    f16x8 b2 = *(const f16x8*)(Wt + (size_t)(col0 + 32 + ar)*128 + kk*32 + ac);
    f16x8 b3 = *(const f16x8*)(Wt + (size_t)(col0 + 48 + ar)*128 + kk*32 + ac);
    acc0 = __builtin_amdgcn_mfma_f32_16x16x32_f16(a, b0, acc0, 0, 0, 0);
    acc1 = __builtin_amdgcn_mfma_f32_16x16x32_f16(a, b1, acc1, 0, 0, 0);
    acc2 = __builtin_amdgcn_mfma_f32_16x16x32_f16(a, b2, acc2, 0, 0, 0);
    acc3 = __builtin_amdgcn_mfma_f32_16x16x32_f16(a, b3, acc3, 0, 0, 0);
  }
  int crow = (l>>4)*4, ccol = l&15;
  #pragma unroll
  for(int r=0; r<4; r++){
    int tr = w*16 + crow + r;
    tile[tr][ccol     ] = __float2half(acc0[r]);
    tile[tr][ccol + 16] = __float2half(acc1[r]);
    tile[tr][ccol + 32] = __float2half(acc2[r]);
    tile[tr][ccol + 48] = __float2half(acc3[r]);
  }
  __syncthreads();
  #pragma unroll
  for(int i=0;i<2;i++){
    int u = threadIdx.x + i*256;
    int row = u>>3, cq = (u&7)*8;
    int grow = rowb + row;
    if(grow < N_NODES)
      *(float4*)(h_all + (size_t)grow*512 + col0 + cq) = *(const float4*)&tile[row][cq];
  }
}

// ---------------- s_src/s_dst: wave per node ----------------
__global__ __launch_bounds__(256) void k_s(const __half* __restrict__ h_all, const float* __restrict__ asrc,
                    const float* __restrict__ adst, float* __restrict__ s_src, float* __restrict__ s_dst){
  int nw = blockIdx.x*4 + (threadIdx.x>>6);
  int l = threadIdx.x&63;
  if(nw >= N_NODES) return;
  int h = l>>4, f8 = (l&15)*8;
  const __half* hp = h_all + (size_t)nw*512 + (h<<7) + f8;
  float4 raw = *(const float4*)hp;
  const __half2* hh = (const __half2*)&raw;
  float2 c0 = __half22float2(hh[0]);
  float2 c1 = __half22float2(hh[1]);
  float2 c2 = __half22float2(hh[2]);
  float2 c3 = __half22float2(hh[3]);
  float4 a0 = *(const float4*)(asrc + (h<<7) + f8);
  float4 a1 = *(const float4*)(asrc + (h<<7) + f8 + 4);
  float4 d0 = *(const float4*)(adst + (h<<7) + f8);
  float4 d1 = *(const float4*)(adst + (h<<7) + f8 + 4);
  float ps = c0.x*a0.x + c0.y*a0.y + c1.x*a0.z + c1.y*a0.w
           + c2.x*a1.x + c2.y*a1.y + c3.x*a1.z + c3.y*a1.w;
  float pd = c0.x*d0.x + c0.y*d0.y + c1.x*d0.z + c1.y*d0.w
           + c2.x*d1.x + c2.y*d1.y + c3.x*d1.z + c3.y*d1.w;
  #pragma unroll
  for(int off=1; off<16; off<<=1){ ps += __shfl_xor(ps,off); pd += __shfl_xor(pd,off); }
  if((l&15)==0){ s_src[nw*4+h] = ps; s_dst[nw*4+h] = pd; }
}

// ---------------- fused softmax + aggregate: wave/node, 2 waves/block, 4-way MLP ----------------
__global__ __launch_bounds__(128) void k_softagg(
    const float* __restrict__ ae, const float* __restrict__ s_src,
    const float* __restrict__ s_dst, const int* __restrict__ sorted_src,
    const int* __restrict__ row_ptr, const __half* __restrict__ h_all,
    float* __restrict__ ew_fb, float* __restrict__ xout, _Float16* __restrict__ xh)
{
  __shared__ float ws4[2][WMAX*4];
  __shared__ int   ssm4[2][WMAX];
  int wv = threadIdx.x>>6, l = threadIdx.x&63;
  int n = blockIdx.x*2 + wv;
  if(n >= N_NODES) return;
  int start = row_ptr[n], end = row_ptr[n+1];
  int deg = end - start;
  bool fits = (deg <= WMAX);
  float* ws = ws4[wv];
  int*   ssm = ssm4[wv];

  float4 sd = *(const float4*)(s_dst + (size_t)n*4);
  float m0=-1e30f, m1=-1e30f, m2=-1e30f, m3=-1e30f;
  float aR[2][4];

  // ---- logits + max ----
  if(fits){
    #pragma unroll
    for(int k=0;k<2;k++){
      int idx = l + k*64;
      if(idx < deg){
        int pos = start + idx;
        int s = sorted_src[pos];
        float4 ss = *(const float4*)(s_src + (size_t)s*4);
        float4 av = *(const float4*)(ae + (size_t)pos*4);
        float a0 = ss.x+sd.x+av.x; a0=(a0>0.f)?a0:0.2f*a0;
        float a1 = ss.y+sd.y+av.y; a1=(a1>0.f)?a1:0.2f*a1;
        float a2 = ss.z+sd.z+av.z; a2=(a2>0.f)?a2:0.2f*a2;
        float a3 = ss.w+sd.w+av.w; a3=(a3>0.f)?a3:0.2f*a3;
        aR[k][0]=a0; aR[k][1]=a1; aR[k][2]=a2; aR[k][3]=a3;
        ssm[idx] = s;
        m0=fmaxf(m0,a0); m1=fmaxf(m1,a1); m2=fmaxf(m2,a2); m3=fmaxf(m3,a3);
      }
    }
  } else {
    for(int pos=start+l; pos<end; pos+=64){
      int s = sorted_src[pos];
      float4 ss = *(const float4*)(s_src + (size_t)s*4);
      float4 av = *(const float4*)(ae + (size_t)pos*4);
      float a0 = ss.x+sd.x+av.x; a0=(a0>0.f)?a0:0.2f*a0;
      float a1 = ss.y+sd.y+av.y; a1=(a1>0.f)?a1:0.2f*a1;
      float a2 = ss.z+sd.z+av.z; a2=(a2>0.f)?a2:0.2f*a2;
      float a3 = ss.w+sd.w+av.w; a3=(a3>0.f)?a3:0.2f*a3;
      *(float4*)(ew_fb + (size_t)pos*4) = make_float4(a0,a1,a2,a3);
      m0=fmaxf(m0,a0); m1=fmaxf(m1,a1); m2=fmaxf(m2,a2); m3=fmaxf(m3,a3);
    }
  }
  #pragma unroll
  for(int off=32; off; off>>=1){
    m0=fmaxf(m0,__shfl_xor(m0,off)); m1=fmaxf(m1,__shfl_xor(m1,off));
    m2=fmaxf(m2,__shfl_xor(m2,off)); m3=fmaxf(m3,__shfl_xor(m3,off));
  }

  // ---- exp + sum ----
  float s0=0.f,s1=0.f,s2=0.f,s3=0.f;
  if(fits){
    #pragma unroll
    for(int k=0;k<2;k++){
      int idx = l + k*64;
      if(idx < deg){
        float w0=__expf(aR[k][0]-m0), w1=__expf(aR[k][1]-m1);
        float w2=__expf(aR[k][2]-m2), w3=__expf(aR[k][3]-m3);
        int sl = idx*4;
        ws[sl]=w0; ws[sl+1]=w1; ws[sl+2]=w2; ws[sl+3]=w3;
        s0+=w0; s1+=w1; s2+=w2; s3+=w3;
      }
    }
  } else {
    for(int pos=start+l; pos<end; pos+=64){
      float4 a = *(const float4*)(ew_fb + (size_t)pos*4);
      float w0=__expf(a.x-m0), w1=__expf(a.y-m1), w2=__expf(a.z-m2), w3=__expf(a.w-m3);
      *(float4*)(ew_fb + (size_t)pos*4) = make_float4(w0,w1,w2,w3);
      s0+=w0; s1+=w1; s2+=w2; s3+=w3;
    }
  }
  #pragma unroll
  for(int off=32; off; off>>=1){
    s0+=__shfl_xor(s0,off); s1+=__shfl_xor(s1,off);
    s2+=__shfl_xor(s2,off); s3+=__shfl_xor(s3,off);
  }

  // ---- gather-aggregate: 4 edges in flight (4 independent acc sets) ----
  int h = l>>4, f8 = (l&15)*8;
  float dh = (h==0)?s0:((h==1)?s1:((h==2)?s2:s3));
  float inv = 1.f/(dh + 1e-16f);
  float ac0[8]={0,0,0,0,0,0,0,0}, ac1[8]={0,0,0,0,0,0,0,0};
  float ac2[8]={0,0,0,0,0,0,0,0}, ac3[8]={0,0,0,0,0,0,0,0};
  int hoff = (h<<7) + f8;
  int sl = 0;
  if(fits){
    for(; sl+4 <= deg; sl+=4){
      int sA = ssm[sl], sB = ssm[sl+1], sC = ssm[sl+2], sD = ssm[sl+3];
      float wA = ws[sl*4+h], wB = ws[(sl+1)*4+h], wC = ws[(sl+2)*4+h], wD = ws[(sl+3)*4+h];
      float4 rA = *(const float4*)(h_all + (size_t)sA*512 + hoff);
      float4 rB = *(const float4*)(h_all + (size_t)sB*512 + hoff);
      float4 rC = *(const float4*)(h_all + (size_t)sC*512 + hoff);
      float4 rD = *(const float4*)(h_all + (size_t)sD*512 + hoff);
      const __half2* hA = (const __half2*)&rA;
      const __half2* hB = (const __half2*)&rB;
      const __half2* hC = (const __half2*)&rC;
      const __half2* hD = (const __half2*)&rD;
      #pragma unroll
      for(int j=0;j<4;j++){
        float2 vA = __half22float2(hA[j]);
        float2 vB = __half22float2(hB[j]);
        float2 vC = __half22float2(hC[j]);
        float2 vD = __half22float2(hD[j]);
        ac0[2*j]+=wA*vA.x; ac0[2*j+1]+=wA*vA.y;
        ac1[2*j]+=wB*vB.x; ac1[2*j+1]+=wB*vB.y;
        ac2[2*j]+=wC*vC.x; ac2[2*j+1]+=wC*vC.y;
        ac3[2*j]+=wD*vD.x; ac3[2*j+1]+=wD*vD.y;
      }
    }
    for(; sl < deg; sl++){
      int s = ssm[sl]; float w = ws[sl*4+h];
      float4 r = *(const float4*)(h_all + (size_t)s*512 + hoff);
      const __half2* hh = (const __half2*)&r;
      #pragma unroll
      for(int j=0;j<4;j++){
        float2 v = __half22float2(hh[j]);
        ac0[2*j]+=w*v.x; ac0[2*j+1]+=w*v.y;
      }
    }
  } else {
    for(; sl < deg; sl++){
      int s = sorted_src[start+sl]; float w = ew_fb[(size_t)(start+sl)*4+h];
      float4 r = *(const float4*)(h_all + (size_t)s*512 + hoff);
      const __half2* hh = (const __half2*)&r;
      #pragma unroll
      for(int j=0;j<4;j++){
        float2 v = __half22float2(hh[j]);
        ac0[2*j]+=w*v.x; ac0[2*j+1]+=w*v.y;
      }
    }
  }
  float acc[8];
  #pragma unroll
  for(int i=0;i<8;i++){
    acc[i] = (ac0[i]+ac1[i]) + (ac2[i]+ac3[i]);
    acc[i] *= inv;
    acc[i] += __shfl_xor(acc[i], 16);
    acc[i] += __shfl_xor(acc[i], 32);
    acc[i] *= 0.25f;
  }
  if(l < 16){
    int f0 = l*8;
    *(float4*)(xout + (size_t)n*128 + f0)     = make_float4(acc[0],acc[1],acc[2],acc[3]);
    *(float4*)(xout + (size_t)n*128 + f0 + 4) = make_float4(acc[4],acc[5],acc[6],acc[7]);
    if(xh){
      f16x8 hv = { (_Float16)acc[0],(_Float16)acc[1],(_Float16)acc[2],(_Float16)acc[3],
                   (_Float16)acc[4],(_Float16)acc[5],(_Float16)acc[6],(_Float16)acc[7] };
      *(f16x8*)(xh + (size_t)n*128 + f0) = hv;
    }
  }
}

// ---------------- gated residual, GEMM-tiled ----------------
__global__ __launch_bounds__(256) void k_gate2(const float* __restrict__ prior, const float* __restrict__ curr,
                       const float* __restrict__ Wp, const float* __restrict__ Wc,
                       float* __restrict__ xnew, _Float16* __restrict__ xh){
  __shared__ float pr[32][132];
  __shared__ float cu[32][132];
  int t = threadIdx.x;
  int n0 = blockIdx.x*32;
  int c0 = blockIdx.y*64;
  #pragma unroll
  for(int i=0;i<4;i++){
    int u = t + i*256;
    int row = u>>5, c4 = (u&31)<<2;
    float4 v = make_float4(0.f,0.f,0.f,0.f), w = v;
    if(n0+row < N_NODES){
      v = *(const float4*)(prior + (size_t)(n0+row)*128 + c4);
      w = *(const float4*)(curr  + (size_t)(n0+row)*128 + c4);
    }
    *(float4*)&pr[row][c4] = v;
    *(float4*)&cu[row][c4] = w;
  }
  __syncthreads();
  int tc = t&15, tr = t>>4;
  int r0 = tr*2, cc = c0 + tc*4;
  float accp[2][4] = {{0.f,0.f,0.f,0.f},{0.f,0.f,0.f,0.f}};
  float accc[2][4] = {{0.f,0.f,0.f,0.f},{0.f,0.f,0.f,0.f}};
  #pragma unroll 4
  for(int k=0;k<128;k++){
    float4 wp = *(const float4*)(Wp + (size_t)k*128 + cc);
    float4 wc = *(const float4*)(Wc + (size_t)k*128 + cc);
    #pragma unroll
    for(int i=0;i<2;i++){
      float ap = pr[r0+i][k], ac = cu[r0+i][k];
      accp[i][0]+=ap*wp.x; accp[i][1]+=ap*wp.y; accp[i][2]+=ap*wp.z; accp[i][3]+=ap*wp.w;
      accc[i][0]+=ac*wc.x; accc[i][1]+=ac*wc.y; accc[i][2]+=ac*wc.z; accc[i][3]+=ac*wc.w;
    }
  }
  #pragma unroll
  for(int i=0;i<2;i++){
    int row = n0 + r0 + i;
    if(row < N_NODES){
      float oj[4];
      #pragma unroll
      for(int j=0;j<4;j++){
        float z = accp[i][j]+accc[i][j];
        float g = 1.f/(1.f+__expf(-z));
        oj[j] = g*cu[r0+i][cc + j] + (1.f-g)*pr[r0+i][cc + j];
      }
      *(float4*)(xnew + (size_t)row*128 + cc) = make_float4(oj[0],oj[1],oj[2],oj[3]);
      if(xh){
        f16x4 hv = { (_Float16)oj[0], (_Float16)oj[1], (_Float16)oj[2], (_Float16)oj[3] };
        *(f16x4*)(xh + (size_t)row*128 + cc) = hv;
      }
    }
  }
}

extern "C" void kernel_launch(void* const* d_in, const int* in_sizes, int n_in,
                              void* d_out, int out_size, void* d_ws, size_t ws_size,
                              hipStream_t stream){
  (void)in_sizes; (void)n_in; (void)out_size; (void)ws_size;
  const float* node_fts = (const float*)d_in[0];
  const float* edge_fts = (const float*)d_in[1];
  const int*   edges    = (const int*)d_in[2];
  const float* Ws       = (const float*)d_in[3];
  const float* Wes      = (const float*)d_in[4];
  const float* a_src    = (const float*)d_in[5];
  const float* a_dst    = (const float*)d_in[6];
  const float* a_edge   = (const float*)d_in[7];
  const float* W_prior  = (const float*)d_in[8];
  const float* W_curr   = (const float*)d_in[9];

  char* ws = (char*)d_ws;
  size_t off = 0;
  auto alloc = [&](size_t bytes)->void*{
    void* p = ws + off;
    off += (bytes + 255) & ~(size_t)255;
    return p;
  };
  int*       counts     = (int*)      alloc((size_t)N_NODES*4);
  int*       row_ptr    = (int*)      alloc((size_t)(N_NODES+1)*4);
  int*       fillp      = (int*)      alloc((size_t)N_NODES*4);
  int*       csr_eid    = (int*)      alloc((size_t)E_EDGES*4);
  int*       sorted_src = (int*)      alloc((size_t)E_EDGES*4);
  float*     b_edge     = (float*)    alloc((size_t)HOPS*64*NH*4);
  float*     ae_sorted  = (float*)    alloc((size_t)HOPS*E_EDGES*NH*4);
  __half*    h_all      = (__half*)   alloc((size_t)N_NODES*512*2);
  float*     s_src      = (float*)    alloc((size_t)N_NODES*NH*4);
  float*     s_dst      = (float*)    alloc((size_t)N_NODES*NH*4);
  float*     ew_fb      = (float*)    alloc((size_t)E_EDGES*NH*4);
  float*     xbuf       = (float*)    alloc((size_t)N_NODES*128*4);
  float*     curbuf     = (float*)    alloc((size_t)N_NODES*128*4);
  _Float16*  xh         = (_Float16*) alloc((size_t)10112*128*2);   // padded rows for MFMA over-read
  _Float16*  WsT        = (_Float16*) alloc((size_t)HOPS*512*128*2);

  const int* src = edges;
  const int* dst = edges + E_EDGES;

  (void)hipMemsetAsync(counts, 0, (size_t)N_NODES*4, stream);
  k_count<<<(E_EDGES+255)/256, 256, 0, stream>>>(dst, counts);
  k_scan<<<1, 1024, 0, stream>>>(counts, row_ptr, fillp);
  k_fill<<<(E_EDGES+255)/256, 256, 0, stream>>>(src, dst, fillp, csr_eid, sorted_src);
  k_setup<<<1349, 256, 0, stream>>>(node_fts, xh, Ws, WsT, Wes, a_edge, b_edge);
  k_alpha_mfma<<<5000, 256, 0, stream>>>(edge_fts, csr_eid, b_edge, ae_sorted);

  for(int hop=0; hop<HOPS; hop++){
    k_projm<<<dim3(157, 8), 256, 0, stream>>>(xh, WsT + (size_t)hop*512*128, h_all);
    k_s<<<2500, 256, 0, stream>>>(h_all, a_src + (size_t)hop*512, a_dst + (size_t)hop*512, s_src, s_dst);
    float* xout = (hop==0) ? xbuf : curbuf;
    k_softagg<<<5000, 128, 0, stream>>>(ae_sorted + (size_t)hop*E_EDGES*4, s_src, s_dst,
                                        sorted_src, row_ptr, h_all, ew_fb, xout,
                                        (hop==0) ? xh : (_Float16*)nullptr);
    if(hop > 0){
      float* xnew = (hop == HOPS-1) ? (float*)d_out : xbuf;
      k_gate2<<<dim3(313, 2), 256, 0, stream>>>(xbuf, curbuf, W_prior, W_curr, xnew,
                                                (hop < HOPS-1) ? xh : (_Float16*)nullptr);
    }
  }
}